// Round 9
// baseline (1016.617 us; speedup 1.0000x reference)
//
#include <hip/hip_runtime.h>
#include <stdint.h>

// Problem dims (fixed by harness)
#define DDIM 1024
#define LSEQ 2048
#define BSZ  8
#define FDIM 4096
#define MROWS (BSZ*LSEQ)   // 16384
#define NCHUNK 32
#define CLEN  (LSEQ/NCHUNK)   // 64

typedef float        f32x4  __attribute__((ext_vector_type(4)));
typedef short        short8 __attribute__((ext_vector_type(8)));

using gas_void = const __attribute__((address_space(1))) void;
using las_void = __attribute__((address_space(3))) void;

__device__ __forceinline__ void gload16(const void* g, void* l) {
    // async global->LDS, 16B per lane; LDS dest = wave-uniform base + lane*16
    __builtin_amdgcn_global_load_lds((gas_void*)g, (las_void*)l, 16, 0, 0);
}

// builtin MFMA: acc lives in AGPRs end-to-end (no accvgpr copies)
__device__ __forceinline__ f32x4 mfma16(short8 a, short8 b, f32x4 c) {
    return __builtin_amdgcn_mfma_f32_16x16x32_bf16(a, b, c, 0, 0, 0);
}

__device__ __forceinline__ unsigned short f2bf(float f) {
    __bf16 h = (__bf16)f;
    return __builtin_bit_cast(unsigned short, h);
}

// ---------------- fused weight fp32 -> bf16 (all 7 matrices, 1 launch) ----------------
struct CvtArgs {
    const float* s[7];
    __bf16*      d[7];
    int          cum[8];   // cumulative float4 counts
};

__global__ __launch_bounds__(256) void cvt_all(CvtArgs a)
{
    const int i = blockIdx.x * 256 + threadIdx.x;
    if (i >= a.cum[7]) return;
    int seg = 0;
#pragma unroll 6
    while (i >= a.cum[seg + 1]) ++seg;
    const int off = i - a.cum[seg];
    float4 f = ((const float4*)a.s[seg])[off];
    ushort4 o;
    o.x = f2bf(f.x); o.y = f2bf(f.y); o.z = f2bf(f.z); o.w = f2bf(f.w);
    ((ushort4*)a.d[seg])[off] = o;
}

// ---------------- block reduce (4 scalars over 256 threads) ----------------
__device__ __forceinline__ void blk_reduce4(float& a, float& b, float& c, float& d) {
#pragma unroll
    for (int off = 32; off >= 1; off >>= 1) {
        a += __shfl_xor(a, off, 64);
        b += __shfl_xor(b, off, 64);
        c += __shfl_xor(c, off, 64);
        d += __shfl_xor(d, off, 64);
    }
    __shared__ float sm[4][4];
    const int tid = threadIdx.x;
    if ((tid & 63) == 0) {
        sm[tid >> 6][0] = a; sm[tid >> 6][1] = b;
        sm[tid >> 6][2] = c; sm[tid >> 6][3] = d;
    }
    __syncthreads();
    a = sm[0][0] + sm[1][0] + sm[2][0] + sm[3][0];
    b = sm[0][1] + sm[1][1] + sm[2][1] + sm[3][1];
    c = sm[0][2] + sm[1][2] + sm[2][2] + sm[3][2];
    d = sm[0][3] + sm[1][3] + sm[2][3] + sm[3][3];
}

// ---------------- LN + time_shift + mix (attention: 3 outputs) ----------------
__global__ __launch_bounds__(256) void ln_mix3(
    const float* __restrict__ xin, const float* __restrict__ lnw, const float* __restrict__ lnb,
    const float* __restrict__ mkv, const float* __restrict__ mvv, const float* __restrict__ mrv,
    __bf16* __restrict__ ok, __bf16* __restrict__ ov, __bf16* __restrict__ orr)
{
    const int row = blockIdx.x;          // b*L + l
    const int l   = row & (LSEQ - 1);
    const int tid = threadIdx.x;
    const size_t rbase = (size_t)row * DDIM;
    const float4 cur = ((const float4*)(xin + rbase))[tid];
    float4 prv = make_float4(0.f, 0.f, 0.f, 0.f);
    if (l > 0) prv = ((const float4*)(xin + rbase - DDIM))[tid];
    float s0 = cur.x + cur.y + cur.z + cur.w;
    float q0 = cur.x*cur.x + cur.y*cur.y + cur.z*cur.z + cur.w*cur.w;
    float s1 = prv.x + prv.y + prv.z + prv.w;
    float q1 = prv.x*prv.x + prv.y*prv.y + prv.z*prv.z + prv.w*prv.w;
    blk_reduce4(s0, q0, s1, q1);
    const float inv = 1.f / (float)DDIM;
    const float m0 = s0 * inv, m1 = s1 * inv;
    const float r0 = rsqrtf(fmaxf(q0 * inv - m0*m0, 0.f) + 1e-5f);
    const float r1 = rsqrtf(fmaxf(q1 * inv - m1*m1, 0.f) + 1e-5f);
    const float4 w4 = ((const float4*)lnw)[tid];
    const float4 b4 = ((const float4*)lnb)[tid];
    const float4 k4 = ((const float4*)mkv)[tid];
    const float4 v4 = ((const float4*)mvv)[tid];
    const float4 r4 = ((const float4*)mrv)[tid];
    const float cA[4] = {cur.x, cur.y, cur.z, cur.w};
    const float pA[4] = {prv.x, prv.y, prv.z, prv.w};
    const float wA[4] = {w4.x, w4.y, w4.z, w4.w};
    const float bA[4] = {b4.x, b4.y, b4.z, b4.w};
    const float kA[4] = {k4.x, k4.y, k4.z, k4.w};
    const float vA[4] = {v4.x, v4.y, v4.z, v4.w};
    const float rA[4] = {r4.x, r4.y, r4.z, r4.w};
    ushort4 pk, pv, pr;
    unsigned short* pkp = &pk.x; unsigned short* pvp = &pv.x; unsigned short* prp = &pr.x;
#pragma unroll
    for (int j = 0; j < 4; ++j) {
        float xa = (cA[j] - m0) * r0 * wA[j] + bA[j];
        float xs = (l > 0) ? ((pA[j] - m1) * r1 * wA[j] + bA[j]) : 0.f;
        pkp[j] = f2bf(xa * kA[j] + xs * (1.f - kA[j]));
        pvp[j] = f2bf(xa * vA[j] + xs * (1.f - vA[j]));
        prp[j] = f2bf(xa * rA[j] + xs * (1.f - rA[j]));
    }
    const size_t oi = (size_t)row * (DDIM/4) + tid;
    ((ushort4*)ok)[oi]  = pk;
    ((ushort4*)ov)[oi]  = pv;
    ((ushort4*)orr)[oi] = pr;
}

// ---------------- LN + time_shift + mix (FFN: 2 outputs) ----------------
__global__ __launch_bounds__(256) void ln_mix2(
    const float* __restrict__ xin, const float* __restrict__ lnw, const float* __restrict__ lnb,
    const float* __restrict__ mkv, const float* __restrict__ mrv,
    __bf16* __restrict__ ok, __bf16* __restrict__ orr)
{
    const int row = blockIdx.x;
    const int l   = row & (LSEQ - 1);
    const int tid = threadIdx.x;
    const size_t rbase = (size_t)row * DDIM;
    const float4 cur = ((const float4*)(xin + rbase))[tid];
    float4 prv = make_float4(0.f, 0.f, 0.f, 0.f);
    if (l > 0) prv = ((const float4*)(xin + rbase - DDIM))[tid];
    float s0 = cur.x + cur.y + cur.z + cur.w;
    float q0 = cur.x*cur.x + cur.y*cur.y + cur.z*cur.z + cur.w*cur.w;
    float s1 = prv.x + prv.y + prv.z + prv.w;
    float q1 = prv.x*prv.x + prv.y*prv.y + prv.z*prv.z + prv.w*prv.w;
    blk_reduce4(s0, q0, s1, q1);
    const float inv = 1.f / (float)DDIM;
    const float m0 = s0 * inv, m1 = s1 * inv;
    const float r0 = rsqrtf(fmaxf(q0 * inv - m0*m0, 0.f) + 1e-5f);
    const float r1 = rsqrtf(fmaxf(q1 * inv - m1*m1, 0.f) + 1e-5f);
    const float4 w4 = ((const float4*)lnw)[tid];
    const float4 b4 = ((const float4*)lnb)[tid];
    const float4 k4 = ((const float4*)mkv)[tid];
    const float4 r4 = ((const float4*)mrv)[tid];
    const float cA[4] = {cur.x, cur.y, cur.z, cur.w};
    const float pA[4] = {prv.x, prv.y, prv.z, prv.w};
    const float wA[4] = {w4.x, w4.y, w4.z, w4.w};
    const float bA[4] = {b4.x, b4.y, b4.z, b4.w};
    const float kA[4] = {k4.x, k4.y, k4.z, k4.w};
    const float rA[4] = {r4.x, r4.y, r4.z, r4.w};
    ushort4 pk, pr;
    unsigned short* pkp = &pk.x; unsigned short* prp = &pr.x;
#pragma unroll
    for (int j = 0; j < 4; ++j) {
        float xa = (cA[j] - m0) * r0 * wA[j] + bA[j];
        float xs = (l > 0) ? ((pA[j] - m1) * r1 * wA[j] + bA[j]) : 0.f;
        pkp[j] = f2bf(xa * kA[j] + xs * (1.f - kA[j]));
        prp[j] = f2bf(xa * rA[j] + xs * (1.f - rA[j]));
    }
    const size_t oi = (size_t)row * (DDIM/4) + tid;
    ((ushort4*)ok)[oi]  = pk;
    ((ushort4*)orr)[oi] = pr;
}

// ---------------- WKV chunk-parallel scan ----------------
__global__ __launch_bounds__(256) void wkv_phase1(
    const __bf16* __restrict__ kin, const __bf16* __restrict__ vin,
    const float* __restrict__ td,
    float* __restrict__ sa, float* __restrict__ sb, float* __restrict__ sp)
{
    const int idx = blockIdx.x * 256 + threadIdx.x;
    const int d  = idx & (DDIM - 1);
    const int bc = idx >> 10;
    const int b  = bc & (BSZ - 1);
    const int c  = bc >> 3;
    const float w = -__expf(td[d]);
    const size_t base = ((size_t)b * LSEQ + (size_t)c * CLEN) * DDIM + d;
    float a = 0.f, bbv = 0.f, p = -1e38f;
    for (int t = 0; t < CLEN; ++t) {
        const size_t off = base + (size_t)t * DDIM;
        const float kt = (float)kin[off];
        const float vt = (float)vin[off];
        const float ww2 = p + w;
        const float q2  = fmaxf(ww2, kt);
        const float e1  = __expf(ww2 - q2);
        const float e2  = __expf(kt - q2);
        a   = e1 * a   + e2 * vt;
        bbv = e1 * bbv + e2;
        p   = q2;
    }
    sa[idx] = a; sb[idx] = bbv; sp[idx] = p;
}

__global__ __launch_bounds__(256) void wkv_phase2(
    const __bf16* __restrict__ kin, const __bf16* __restrict__ vin,
    const __bf16* __restrict__ srin,
    const float* __restrict__ td, const float* __restrict__ tf,
    const float* __restrict__ sa, const float* __restrict__ sb,
    const float* __restrict__ sp,
    __bf16* __restrict__ outp)
{
    const int idx = blockIdx.x * 256 + threadIdx.x;
    const int d  = idx & (DDIM - 1);
    const int bc = idx >> 10;
    const int b  = bc & (BSZ - 1);
    const int c  = bc >> 3;
    const float w = -__expf(td[d]);
    const float u = tf[d];
    const float nw = (float)CLEN * w;

    float a = 0.f, bbv = 0.f, p = -1e38f;
    for (int j = 0; j < c; ++j) {
        const int sidx = ((j * BSZ + b) << 10) + d;
        const float aj = sa[sidx], bj = sb[sidx], pj = sp[sidx];
        const float ps = p + nw;
        const float pn = fmaxf(ps, pj);
        const float e1 = __expf(ps - pn);
        const float e2 = __expf(pj - pn);
        a   = e1 * a   + e2 * aj;
        bbv = e1 * bbv + e2 * bj;
        p   = pn;
    }

    const size_t base = ((size_t)b * LSEQ + (size_t)c * CLEN) * DDIM + d;
    for (int t = 0; t < CLEN; ++t) {
        const size_t off = base + (size_t)t * DDIM;
        const float kt = (float)kin[off];
        const float vt = (float)vin[off];
        const float sr = (float)srin[off];
        const float ww = u + kt;
        const float q  = fmaxf(p, ww);
        const float e1 = __expf(p - q);
        const float e2 = __expf(ww - q);
        const float o  = (e1 * a + e2 * vt) / (e1 * bbv + e2);
        outp[off] = (__bf16)(sr * o);
        const float ww2 = p + w;
        const float q2  = fmaxf(ww2, kt);
        const float e1b = __expf(ww2 - q2);
        const float e2b = __expf(kt - q2);
        a   = e1b * a   + e2b * vt;
        bbv = e1b * bbv + e2b;
        p   = q2;
    }
}

// ---------------- m97-replica bf16 GEMM: C[M,N] = A[M,K] @ B[N,K]^T ----------------
// 128x128 tile, BK=32, 4 waves (2x2), single-buffered 16KiB LDS, 2 syncthreads/step,
// global_load_lds width=16, builtin MFMA (acc in AGPRs), ~3 blocks/CU TLP.
// EPI: 1 sigmoid->bf16; 2 relu^2->bf16; 3 auxF+acc->f32; 4 auxF+auxH*acc->f32; 5 bf16
template<int EPI>
__global__ __launch_bounds__(256)
void gemm_bt(const __bf16* __restrict__ A, const __bf16* __restrict__ Bw,
             float* outF, __bf16* outH,
             const float* auxF, const __bf16* __restrict__ auxH,
             int N, int K)
{
    __shared__ __bf16 As[128 * 32];
    __shared__ __bf16 Bs[128 * 32];
    const int tid  = threadIdx.x;
    const int lane = tid & 63;
    const int wid  = tid >> 6;
    const int wr = wid >> 1, wc = wid & 1;
    const size_t row0 = (size_t)blockIdx.x * 128;
    const size_t col0 = (size_t)blockIdx.y * 128;

    // staging: chunk c covers 16 rows; lane -> (row=l>>2, col8=(l&3)*8); LDS linear
    const int c0 = wid * 2, c1 = c0 + 1;
    const int srow = lane >> 2;
    const int scol = (lane & 3) << 3;
    const __bf16* aG0 = A  + (row0 + c0 * 16 + srow) * (size_t)K + scol;
    const __bf16* aG1 = A  + (row0 + c1 * 16 + srow) * (size_t)K + scol;
    const __bf16* bG0 = Bw + (col0 + c0 * 16 + srow) * (size_t)K + scol;
    const __bf16* bG1 = Bw + (col0 + c1 * 16 + srow) * (size_t)K + scol;
    __bf16* aL0 = &As[c0 * 512];
    __bf16* aL1 = &As[c1 * 512];
    __bf16* bL0 = &Bs[c0 * 512];
    __bf16* bL1 = &Bs[c1 * 512];

    f32x4 acc[4][4] = {};

    // fragment: row = lane&15 within 16-row subtile, k = 8*(lane>>4)+0..7 (contiguous)
    const int aoff = (wr * 64 + (lane & 15)) * 32 + ((lane >> 4) << 3);
    const int boff = (wc * 64 + (lane & 15)) * 32 + ((lane >> 4) << 3);

    for (int k0 = 0; k0 < K; k0 += 32) {
        __syncthreads();                  // previous reads done before overwrite
        gload16(aG0 + k0, aL0);
        gload16(aG1 + k0, aL1);
        gload16(bG0 + k0, bL0);
        gload16(bG1 + k0, bL1);
        __syncthreads();                  // drains vmcnt(0), publishes tile
        short8 af[4], bf[4];
#pragma unroll
        for (int m = 0; m < 4; ++m) af[m] = *(const short8*)&As[aoff + m * 512];
#pragma unroll
        for (int n = 0; n < 4; ++n) bf[n] = *(const short8*)&Bs[boff + n * 512];
#pragma unroll
        for (int m = 0; m < 4; ++m)
#pragma unroll
            for (int n = 0; n < 4; ++n)
                acc[m][n] = mfma16(af[m], bf[n], acc[m][n]);
    }

    // C/D layout: col = lane&15, row = 4*(lane>>4) + reg   [verified r2-r8]
    const size_t obr = row0 + wr * 64 + ((lane >> 4) << 2);
    const size_t obc = col0 + wc * 64 + (lane & 15);
#pragma unroll
    for (int m = 0; m < 4; ++m) {
#pragma unroll
        for (int n = 0; n < 4; ++n) {
#pragma unroll
            for (int j = 0; j < 4; ++j) {
                const size_t idx = (obr + m * 16 + j) * (size_t)N + obc + n * 16;
                const float v = acc[m][n][j];
                if constexpr (EPI == 1) {
                    outH[idx] = (__bf16)(1.f / (1.f + __expf(-v)));
                } else if constexpr (EPI == 2) {
                    const float t = fmaxf(v, 0.f);
                    outH[idx] = (__bf16)(t * t);
                } else if constexpr (EPI == 3) {
                    outF[idx] = auxF[idx] + v;
                } else if constexpr (EPI == 4) {
                    outF[idx] = auxF[idx] + (float)auxH[idx] * v;
                } else {
                    outH[idx] = (__bf16)v;
                }
            }
        }
    }
}

extern "C" void kernel_launch(void* const* d_in, const int* in_sizes, int n_in,
                              void* d_out, int out_size, void* d_ws, size_t ws_size,
                              hipStream_t stream)
{
    const float* x    = (const float*)d_in[0];
    const float* lnaw = (const float*)d_in[1];
    const float* lnab = (const float*)d_in[2];
    const float* lnfw = (const float*)d_in[3];
    const float* lnfb = (const float*)d_in[4];
    const float* tdec = (const float*)d_in[5];
    const float* tfir = (const float*)d_in[6];
    const float* amk  = (const float*)d_in[7];
    const float* amv  = (const float*)d_in[8];
    const float* amr  = (const float*)d_in[9];
    const float* aWk  = (const float*)d_in[10];
    const float* aWv  = (const float*)d_in[11];
    const float* aWr  = (const float*)d_in[12];
    const float* aWo  = (const float*)d_in[13];
    const float* fmk  = (const float*)d_in[14];
    const float* fmr  = (const float*)d_in[15];
    const float* fWk  = (const float*)d_in[16];
    const float* fWv  = (const float*)d_in[17];
    const float* fWr  = (const float*)d_in[18];
    float* out = (float*)d_out;

    char* ws = (char*)d_ws;
    const size_t MiB = 1ull << 20;
    __bf16* Wk_h  = (__bf16*)ws;
    __bf16* Wv_h  = Wk_h + (1ull << 20);
    __bf16* Wr_h  = Wk_h + (2ull << 20);
    __bf16* Wo_h  = Wk_h + (3ull << 20);
    __bf16* fWk_h = Wk_h + (4ull << 20);
    __bf16* fWv_h = Wk_h + (8ull << 20);
    __bf16* fWr_h = Wk_h + (12ull << 20);
    // activations — peak ws extent = 221 MiB
    __bf16* xk = (__bf16*)(ws + 26 * MiB);
    __bf16* xv = (__bf16*)(ws + 58 * MiB);
    __bf16* xr = (__bf16*)(ws + 90 * MiB);
    __bf16* kb = (__bf16*)(ws + 122 * MiB);
    __bf16* vb = (__bf16*)(ws + 154 * MiB);
    __bf16* sr = (__bf16*)(ws + 186 * MiB);
    float* st_a = (float*)(ws + 218 * MiB);
    float* st_b = (float*)(ws + 219 * MiB);
    float* st_p = (float*)(ws + 220 * MiB);
    __bf16* atta = xk;
    __bf16* kx   = xv;
    __bf16* rx   = xr;
    __bf16* sb   = xk;
    __bf16* hb   = (__bf16*)(ws + 90 * MiB);

    // 1. weights -> bf16 (single fused launch)
    CvtArgs ca;
    ca.s[0] = aWk;  ca.d[0] = Wk_h;
    ca.s[1] = aWv;  ca.d[1] = Wv_h;
    ca.s[2] = aWr;  ca.d[2] = Wr_h;
    ca.s[3] = aWo;  ca.d[3] = Wo_h;
    ca.s[4] = fWk;  ca.d[4] = fWk_h;
    ca.s[5] = fWv;  ca.d[5] = fWv_h;
    ca.s[6] = fWr;  ca.d[6] = fWr_h;
    {
        const int sz[7] = {1<<18, 1<<18, 1<<18, 1<<18, 1<<20, 1<<20, 1<<18};
        int c = 0;
        for (int i = 0; i < 7; ++i) { ca.cum[i] = c; c += sz[i]; }
        ca.cum[7] = c;   // 3407872 float4s
    }
    cvt_all<<<(ca.cum[7] + 255) / 256, 256, 0, stream>>>(ca);

    // 2. attention LN + shift + mix
    ln_mix3<<<MROWS, 256, 0, stream>>>(x, lnaw, lnab, amk, amv, amr, xk, xv, xr);

    // 3. k, v (bf16), sigmoid(r)
    dim3 blk(256);
    dim3 gD(MROWS / 128, DDIM / 128);   // 128 x 8
    dim3 gF(MROWS / 128, FDIM / 128);   // 128 x 32
    gemm_bt<5><<<gD, blk, 0, stream>>>(xk, Wk_h, nullptr, kb, nullptr, nullptr, DDIM, DDIM);
    gemm_bt<5><<<gD, blk, 0, stream>>>(xv, Wv_h, nullptr, vb, nullptr, nullptr, DDIM, DDIM);
    gemm_bt<1><<<gD, blk, 0, stream>>>(xr, Wr_h, nullptr, sr, nullptr, nullptr, DDIM, DDIM);

    // 4. WKV chunk-parallel scan -> sigmoid(r) * wkv (bf16), into xk region
    const int nthreads = BSZ * DDIM * NCHUNK;
    wkv_phase1<<<nthreads / 256, 256, 0, stream>>>(kb, vb, tdec, st_a, st_b, st_p);
    wkv_phase2<<<nthreads / 256, 256, 0, stream>>>(kb, vb, sr, tdec, tfir,
                                                   st_a, st_b, st_p, atta);

    // 5. att output projection + residual -> d_out (= x_new)
    gemm_bt<3><<<gD, blk, 0, stream>>>(atta, Wo_h, out, nullptr, x, nullptr, DDIM, DDIM);

    // 6. FFN LN + shift + mix (reads d_out)
    ln_mix2<<<MROWS, 256, 0, stream>>>(out, lnfw, lnfb, fmk, fmr, kx, rx);

    // 7a. s = sigmoid(rx @ fWr^T)  (before h so rx region can be reused)
    gemm_bt<1><<<gD, blk, 0, stream>>>(rx, fWr_h, nullptr, sb, nullptr, nullptr, DDIM, DDIM);

    // 7b. h = relu(kx @ fWk^T)^2
    gemm_bt<2><<<gF, blk, 0, stream>>>(kx, fWk_h, nullptr, hb, nullptr, nullptr, FDIM, DDIM);

    // 8. d_out = x_new + s * (h @ fWv^T)
    gemm_bt<4><<<gD, blk, 0, stream>>>(hb, fWv_h, out, nullptr, out, sb, DDIM, FDIM);
}

// Round 10
// 714.981 us; speedup vs baseline: 1.4219x; 1.4219x over previous
//
#include <hip/hip_runtime.h>
#include <stdint.h>

// Problem dims (fixed by harness)
#define DDIM 1024
#define LSEQ 2048
#define BSZ  8
#define FDIM 4096
#define MROWS (BSZ*LSEQ)   // 16384
#define NCHUNK 32
#define CLEN  (LSEQ/NCHUNK)   // 64

typedef float        f32x4  __attribute__((ext_vector_type(4)));
typedef short        short8 __attribute__((ext_vector_type(8)));

using gas_void = const __attribute__((address_space(1))) void;
using las_void = __attribute__((address_space(3))) void;

__device__ __forceinline__ void gload16(const void* g, void* l) {
    __builtin_amdgcn_global_load_lds((gas_void*)g, (las_void*)l, 16, 0, 0);
}

__device__ __forceinline__ f32x4 mfma16(short8 a, short8 b, f32x4 c) {
    return __builtin_amdgcn_mfma_f32_16x16x32_bf16(a, b, c, 0, 0, 0);
}

__device__ __forceinline__ unsigned short f2bf(float f) {
    __bf16 h = (__bf16)f;
    return __builtin_bit_cast(unsigned short, h);
}

// ---------------- fused weight fp32 -> bf16 (all 7 matrices, 1 launch) ----------------
struct CvtArgs {
    const float* s[7];
    __bf16*      d[7];
    int          cum[8];
};

__global__ __launch_bounds__(256) void cvt_all(CvtArgs a)
{
    const int i = blockIdx.x * 256 + threadIdx.x;
    if (i >= a.cum[7]) return;
    int seg = 0;
#pragma unroll 6
    while (i >= a.cum[seg + 1]) ++seg;
    const int off = i - a.cum[seg];
    float4 f = ((const float4*)a.s[seg])[off];
    ushort4 o;
    o.x = f2bf(f.x); o.y = f2bf(f.y); o.z = f2bf(f.z); o.w = f2bf(f.w);
    ((ushort4*)a.d[seg])[off] = o;
}

// ---------------- block reduce (4 scalars over 256 threads) ----------------
__device__ __forceinline__ void blk_reduce4(float& a, float& b, float& c, float& d) {
#pragma unroll
    for (int off = 32; off >= 1; off >>= 1) {
        a += __shfl_xor(a, off, 64);
        b += __shfl_xor(b, off, 64);
        c += __shfl_xor(c, off, 64);
        d += __shfl_xor(d, off, 64);
    }
    __shared__ float sm[4][4];
    const int tid = threadIdx.x;
    if ((tid & 63) == 0) {
        sm[tid >> 6][0] = a; sm[tid >> 6][1] = b;
        sm[tid >> 6][2] = c; sm[tid >> 6][3] = d;
    }
    __syncthreads();
    a = sm[0][0] + sm[1][0] + sm[2][0] + sm[3][0];
    b = sm[0][1] + sm[1][1] + sm[2][1] + sm[3][1];
    c = sm[0][2] + sm[1][2] + sm[2][2] + sm[3][2];
    d = sm[0][3] + sm[1][3] + sm[2][3] + sm[3][3];
}

// ---------------- LN + time_shift + mix (attention: 3 outputs) ----------------
__global__ __launch_bounds__(256) void ln_mix3(
    const float* __restrict__ xin, const float* __restrict__ lnw, const float* __restrict__ lnb,
    const float* __restrict__ mkv, const float* __restrict__ mvv, const float* __restrict__ mrv,
    __bf16* __restrict__ ok, __bf16* __restrict__ ov, __bf16* __restrict__ orr)
{
    const int row = blockIdx.x;
    const int l   = row & (LSEQ - 1);
    const int tid = threadIdx.x;
    const size_t rbase = (size_t)row * DDIM;
    const float4 cur = ((const float4*)(xin + rbase))[tid];
    float4 prv = make_float4(0.f, 0.f, 0.f, 0.f);
    if (l > 0) prv = ((const float4*)(xin + rbase - DDIM))[tid];
    float s0 = cur.x + cur.y + cur.z + cur.w;
    float q0 = cur.x*cur.x + cur.y*cur.y + cur.z*cur.z + cur.w*cur.w;
    float s1 = prv.x + prv.y + prv.z + prv.w;
    float q1 = prv.x*prv.x + prv.y*prv.y + prv.z*prv.z + prv.w*prv.w;
    blk_reduce4(s0, q0, s1, q1);
    const float inv = 1.f / (float)DDIM;
    const float m0 = s0 * inv, m1 = s1 * inv;
    const float r0 = rsqrtf(fmaxf(q0 * inv - m0*m0, 0.f) + 1e-5f);
    const float r1 = rsqrtf(fmaxf(q1 * inv - m1*m1, 0.f) + 1e-5f);
    const float4 w4 = ((const float4*)lnw)[tid];
    const float4 b4 = ((const float4*)lnb)[tid];
    const float4 k4 = ((const float4*)mkv)[tid];
    const float4 v4 = ((const float4*)mvv)[tid];
    const float4 r4 = ((const float4*)mrv)[tid];
    const float cA[4] = {cur.x, cur.y, cur.z, cur.w};
    const float pA[4] = {prv.x, prv.y, prv.z, prv.w};
    const float wA[4] = {w4.x, w4.y, w4.z, w4.w};
    const float bA[4] = {b4.x, b4.y, b4.z, b4.w};
    const float kA[4] = {k4.x, k4.y, k4.z, k4.w};
    const float vA[4] = {v4.x, v4.y, v4.z, v4.w};
    const float rA[4] = {r4.x, r4.y, r4.z, r4.w};
    ushort4 pk, pv, pr;
    unsigned short* pkp = &pk.x; unsigned short* pvp = &pv.x; unsigned short* prp = &pr.x;
#pragma unroll
    for (int j = 0; j < 4; ++j) {
        float xa = (cA[j] - m0) * r0 * wA[j] + bA[j];
        float xs = (l > 0) ? ((pA[j] - m1) * r1 * wA[j] + bA[j]) : 0.f;
        pkp[j] = f2bf(xa * kA[j] + xs * (1.f - kA[j]));
        pvp[j] = f2bf(xa * vA[j] + xs * (1.f - vA[j]));
        prp[j] = f2bf(xa * rA[j] + xs * (1.f - rA[j]));
    }
    const size_t oi = (size_t)row * (DDIM/4) + tid;
    ((ushort4*)ok)[oi]  = pk;
    ((ushort4*)ov)[oi]  = pv;
    ((ushort4*)orr)[oi] = pr;
}

// ---------------- LN + time_shift + mix (FFN: 2 outputs) ----------------
__global__ __launch_bounds__(256) void ln_mix2(
    const float* __restrict__ xin, const float* __restrict__ lnw, const float* __restrict__ lnb,
    const float* __restrict__ mkv, const float* __restrict__ mrv,
    __bf16* __restrict__ ok, __bf16* __restrict__ orr)
{
    const int row = blockIdx.x;
    const int l   = row & (LSEQ - 1);
    const int tid = threadIdx.x;
    const size_t rbase = (size_t)row * DDIM;
    const float4 cur = ((const float4*)(xin + rbase))[tid];
    float4 prv = make_float4(0.f, 0.f, 0.f, 0.f);
    if (l > 0) prv = ((const float4*)(xin + rbase - DDIM))[tid];
    float s0 = cur.x + cur.y + cur.z + cur.w;
    float q0 = cur.x*cur.x + cur.y*cur.y + cur.z*cur.z + cur.w*cur.w;
    float s1 = prv.x + prv.y + prv.z + prv.w;
    float q1 = prv.x*prv.x + prv.y*prv.y + prv.z*prv.z + prv.w*prv.w;
    blk_reduce4(s0, q0, s1, q1);
    const float inv = 1.f / (float)DDIM;
    const float m0 = s0 * inv, m1 = s1 * inv;
    const float r0 = rsqrtf(fmaxf(q0 * inv - m0*m0, 0.f) + 1e-5f);
    const float r1 = rsqrtf(fmaxf(q1 * inv - m1*m1, 0.f) + 1e-5f);
    const float4 w4 = ((const float4*)lnw)[tid];
    const float4 b4 = ((const float4*)lnb)[tid];
    const float4 k4 = ((const float4*)mkv)[tid];
    const float4 r4 = ((const float4*)mrv)[tid];
    const float cA[4] = {cur.x, cur.y, cur.z, cur.w};
    const float pA[4] = {prv.x, prv.y, prv.z, prv.w};
    const float wA[4] = {w4.x, w4.y, w4.z, w4.w};
    const float bA[4] = {b4.x, b4.y, b4.z, b4.w};
    const float kA[4] = {k4.x, k4.y, k4.z, k4.w};
    const float rA[4] = {r4.x, r4.y, r4.z, r4.w};
    ushort4 pk, pr;
    unsigned short* pkp = &pk.x; unsigned short* prp = &pr.x;
#pragma unroll
    for (int j = 0; j < 4; ++j) {
        float xa = (cA[j] - m0) * r0 * wA[j] + bA[j];
        float xs = (l > 0) ? ((pA[j] - m1) * r1 * wA[j] + bA[j]) : 0.f;
        pkp[j] = f2bf(xa * kA[j] + xs * (1.f - kA[j]));
        prp[j] = f2bf(xa * rA[j] + xs * (1.f - rA[j]));
    }
    const size_t oi = (size_t)row * (DDIM/4) + tid;
    ((ushort4*)ok)[oi]  = pk;
    ((ushort4*)orr)[oi] = pr;
}

// ---------------- WKV chunk-parallel scan ----------------
__global__ __launch_bounds__(256) void wkv_phase1(
    const __bf16* __restrict__ kin, const __bf16* __restrict__ vin,
    const float* __restrict__ td,
    float* __restrict__ sa, float* __restrict__ sb, float* __restrict__ sp)
{
    const int idx = blockIdx.x * 256 + threadIdx.x;
    const int d  = idx & (DDIM - 1);
    const int bc = idx >> 10;
    const int b  = bc & (BSZ - 1);
    const int c  = bc >> 3;
    const float w = -__expf(td[d]);
    const size_t base = ((size_t)b * LSEQ + (size_t)c * CLEN) * DDIM + d;
    float a = 0.f, bbv = 0.f, p = -1e38f;
    for (int t = 0; t < CLEN; ++t) {
        const size_t off = base + (size_t)t * DDIM;
        const float kt = (float)kin[off];
        const float vt = (float)vin[off];
        const float ww2 = p + w;
        const float q2  = fmaxf(ww2, kt);
        const float e1  = __expf(ww2 - q2);
        const float e2  = __expf(kt - q2);
        a   = e1 * a   + e2 * vt;
        bbv = e1 * bbv + e2;
        p   = q2;
    }
    sa[idx] = a; sb[idx] = bbv; sp[idx] = p;
}

__global__ __launch_bounds__(256) void wkv_phase2(
    const __bf16* __restrict__ kin, const __bf16* __restrict__ vin,
    const __bf16* __restrict__ srin,
    const float* __restrict__ td, const float* __restrict__ tf,
    const float* __restrict__ sa, const float* __restrict__ sb,
    const float* __restrict__ sp,
    __bf16* __restrict__ outp)
{
    const int idx = blockIdx.x * 256 + threadIdx.x;
    const int d  = idx & (DDIM - 1);
    const int bc = idx >> 10;
    const int b  = bc & (BSZ - 1);
    const int c  = bc >> 3;
    const float w = -__expf(td[d]);
    const float u = tf[d];
    const float nw = (float)CLEN * w;

    float a = 0.f, bbv = 0.f, p = -1e38f;
    for (int j = 0; j < c; ++j) {
        const int sidx = ((j * BSZ + b) << 10) + d;
        const float aj = sa[sidx], bj = sb[sidx], pj = sp[sidx];
        const float ps = p + nw;
        const float pn = fmaxf(ps, pj);
        const float e1 = __expf(ps - pn);
        const float e2 = __expf(pj - pn);
        a   = e1 * a   + e2 * aj;
        bbv = e1 * bbv + e2 * bj;
        p   = pn;
    }

    const size_t base = ((size_t)b * LSEQ + (size_t)c * CLEN) * DDIM + d;
    for (int t = 0; t < CLEN; ++t) {
        const size_t off = base + (size_t)t * DDIM;
        const float kt = (float)kin[off];
        const float vt = (float)vin[off];
        const float sr = (float)srin[off];
        const float ww = u + kt;
        const float q  = fmaxf(p, ww);
        const float e1 = __expf(p - q);
        const float e2 = __expf(ww - q);
        const float o  = (e1 * a + e2 * vt) / (e1 * bbv + e2);
        outp[off] = (__bf16)(sr * o);
        const float ww2 = p + w;
        const float q2  = fmaxf(ww2, kt);
        const float e1b = __expf(ww2 - q2);
        const float e2b = __expf(kt - q2);
        a   = e1b * a   + e2b * vt;
        bbv = e1b * bbv + e2b;
        p   = q2;
    }
}

// ---------------- 256x256 8-phase bf16 GEMM, v4: ONE barrier per phase ----------------
// C[M,N] = A[M,K] @ B[N,K]^T. 8 waves (2Mx4N), BK=64 (2x32-k halves), 2 K-tile dbuf,
// 8 phases/iter, vmcnt(6) at ph1/ph5 tops, setprio, swizzled LDS, builtin MFMA.
// Safety (1 barrier/phase): a wave reaching phase p+1's barrier has consumed its
// phase-p ds_reads via MFMA (lgkm dep), so stages issued after that barrier cannot
// overwrite live data. Each region's stage lands exactly one phase after last read.
// EPI: 1 sigmoid->bf16; 2 relu^2->bf16; 3 auxF+acc->f32; 4 auxF+auxH*acc->f32;
//      5 bf16; 7 kvr-merged (3 slabs of 256 blocks; slab2 sigmoid)
template<int EPI>
__global__ __launch_bounds__(512, 2)
void gemm8(const __bf16* __restrict__ A, const __bf16* __restrict__ Bw,
           float* outF, __bf16* outH,
           const float* auxF, const __bf16* __restrict__ auxH,
           int N, int K, int gy)
{
    __shared__ __align__(16) char smem[131072];
    const int tid  = threadIdx.x;
    const int lane = tid & 63;
    const int wid  = tid >> 6;
    const int wr = wid >> 2, wc = wid & 3;

    int f = blockIdx.x;
    int nwg = gridDim.x;
    bool sig = false;
    if constexpr (EPI == 7) {
        const int slab = f >> 8;
        f &= 255; nwg = 256;
        A    += (size_t)slab * (16u << 20);   // xk/xv/xr stride 16M elems
        Bw   += (size_t)slab << 20;           // Wk|Wv|Wr stride 1M elems
        outH += (size_t)slab << 24;           // kb|vb|sr stride 16M elems
        sig = (slab == 2);
    }
    // T1: XCD-bijective remap (nwg % 8 == 0), gy-major for A-panel L2 reuse
    const int g = (f & 7) * (nwg >> 3) + (f >> 3);
    const int tx = g / gy;
    const int ty = g - tx * gy;
    const size_t row0 = (size_t)tx * 256;
    const size_t col0 = (size_t)ty * 256;

    const int nt = K >> 6;
    const int iters = K >> 7;

    auto stage_half = [&](int d, int X, int kh, int ktile) {
        const int kc = (ktile < nt ? ktile : nt - 1);
        const int kg = kc * 64 + kh * 32;
#pragma unroll
        for (int q = 0; q < 2; ++q) {
            const int row   = q * 128 + wid * 16 + (lane >> 2);
            const int chunk = (lane & 3) ^ ((row >> 1) & 3);
            const __bf16* gp = (X ? Bw + (col0 + row) * (size_t)K
                                  : A  + (row0 + row) * (size_t)K) + kg + chunk * 8;
            char* lp = smem + d * 65536 + X * 32768 + kh * 16384 + q * 8192 + wid * 1024;
            gload16(gp, lp);
        }
    };
    auto rdA = [&](int d, int ks, int m) -> short8 {
        const int row  = wr * 128 + m * 16 + (lane & 15);
        const int slot = (lane >> 4) ^ ((row >> 1) & 3);
        return *(const short8*)(smem + d * 65536 + ks * 16384 + row * 64 + slot * 16);
    };
    auto rdB = [&](int d, int ks, int n) -> short8 {
        const int row  = wc * 64 + n * 16 + (lane & 15);
        const int slot = (lane >> 4) ^ ((row >> 1) & 3);
        return *(const short8*)(smem + d * 65536 + 32768 + ks * 16384 + row * 64 + slot * 16);
    };

    f32x4 acc[8][4] = {};
    short8 bfr[4];

#define VM6 asm volatile("s_waitcnt vmcnt(6)" ::: "memory")

// One phase, single barrier: {VMW; barrier; reads; stage; setprio MFMA}
#define PHASE(d, ks, mh, RD8, STAGE_STMT, VMW)                                   \
    {                                                                            \
        VMW;                                                                     \
        __builtin_amdgcn_s_barrier();                                            \
        short8 afr[4];                                                           \
        _Pragma("unroll")                                                        \
        for (int m = 0; m < 4; ++m) afr[m] = rdA(d, ks, (mh) * 4 + m);           \
        if (RD8) {                                                               \
            _Pragma("unroll")                                                    \
            for (int n = 0; n < 4; ++n) bfr[n] = rdB(d, ks, n);                  \
        }                                                                        \
        STAGE_STMT;                                                              \
        __builtin_amdgcn_s_setprio(1);                                           \
        _Pragma("unroll")                                                        \
        for (int m = 0; m < 4; ++m) {                                            \
            _Pragma("unroll")                                                    \
            for (int n = 0; n < 4; ++n)                                          \
                acc[(mh) * 4 + m][n] = mfma16(afr[m], bfr[n], acc[(mh) * 4 + m][n]); \
        }                                                                        \
        __builtin_amdgcn_s_setprio(0);                                           \
    }

    // prologue: T0 all 4 halves -> buf0; T1 {B.kh0, A.kh0, B.kh1} -> buf1
    stage_half(0, 0, 0, 0); stage_half(0, 0, 1, 0);
    stage_half(0, 1, 0, 0); stage_half(0, 1, 1, 0);
    stage_half(1, 1, 0, 1); stage_half(1, 0, 0, 1); stage_half(1, 1, 1, 1);

    for (int it = 0; it < iters; ++it) {
        const int kt = 2 * it;
        PHASE(0, 0, 0, 1, stage_half(1, 0, 1, kt + 1), VM6);     // ph1 (T0/T2 ready)
        PHASE(0, 0, 1, 0, stage_half(0, 1, 0, kt + 2), );        // ph2
        PHASE(0, 1, 0, 1, stage_half(0, 0, 0, kt + 2), );        // ph3
        PHASE(0, 1, 1, 0, stage_half(0, 1, 1, kt + 2), );        // ph4
        PHASE(1, 0, 0, 1, stage_half(0, 0, 1, kt + 2), VM6);     // ph5 (T1/T3 ready)
        PHASE(1, 0, 1, 0, stage_half(1, 1, 0, kt + 3), );        // ph6
        PHASE(1, 1, 0, 1, stage_half(1, 0, 0, kt + 3), );        // ph7
        PHASE(1, 1, 1, 0, stage_half(1, 1, 1, kt + 3), );        // ph8
    }
#undef PHASE
#undef VM6

    // C/D layout: col = lane&15, row = 4*(lane>>4) + reg  [verified r2-r9]
    const size_t obr = row0 + wr * 128 + ((lane >> 4) << 2);
    const size_t obc = col0 + wc * 64 + (lane & 15);
#pragma unroll
    for (int m = 0; m < 8; ++m) {
#pragma unroll
        for (int n = 0; n < 4; ++n) {
#pragma unroll
            for (int j = 0; j < 4; ++j) {
                const size_t idx = (obr + m * 16 + j) * (size_t)N + obc + n * 16;
                const float v = acc[m][n][j];
                if constexpr (EPI == 1) {
                    outH[idx] = (__bf16)(1.f / (1.f + __expf(-v)));
                } else if constexpr (EPI == 2) {
                    const float t2 = fmaxf(v, 0.f);
                    outH[idx] = (__bf16)(t2 * t2);
                } else if constexpr (EPI == 3) {
                    outF[idx] = auxF[idx] + v;
                } else if constexpr (EPI == 4) {
                    outF[idx] = auxF[idx] + (float)auxH[idx] * v;
                } else if constexpr (EPI == 7) {
                    outH[idx] = (__bf16)(sig ? (1.f / (1.f + __expf(-v))) : v);
                } else {
                    outH[idx] = (__bf16)v;
                }
            }
        }
    }
}

extern "C" void kernel_launch(void* const* d_in, const int* in_sizes, int n_in,
                              void* d_out, int out_size, void* d_ws, size_t ws_size,
                              hipStream_t stream)
{
    const float* x    = (const float*)d_in[0];
    const float* lnaw = (const float*)d_in[1];
    const float* lnab = (const float*)d_in[2];
    const float* lnfw = (const float*)d_in[3];
    const float* lnfb = (const float*)d_in[4];
    const float* tdec = (const float*)d_in[5];
    const float* tfir = (const float*)d_in[6];
    const float* amk  = (const float*)d_in[7];
    const float* amv  = (const float*)d_in[8];
    const float* amr  = (const float*)d_in[9];
    const float* aWk  = (const float*)d_in[10];
    const float* aWv  = (const float*)d_in[11];
    const float* aWr  = (const float*)d_in[12];
    const float* aWo  = (const float*)d_in[13];
    const float* fmk  = (const float*)d_in[14];
    const float* fmr  = (const float*)d_in[15];
    const float* fWk  = (const float*)d_in[16];
    const float* fWv  = (const float*)d_in[17];
    const float* fWr  = (const float*)d_in[18];
    float* out = (float*)d_out;

    char* ws = (char*)d_ws;
    const size_t MiB = 1ull << 20;
    __bf16* Wk_h  = (__bf16*)ws;
    __bf16* Wv_h  = Wk_h + (1ull << 20);
    __bf16* Wr_h  = Wk_h + (2ull << 20);
    __bf16* Wo_h  = Wk_h + (3ull << 20);
    __bf16* fWk_h = Wk_h + (4ull << 20);
    __bf16* fWv_h = Wk_h + (8ull << 20);
    __bf16* fWr_h = Wk_h + (12ull << 20);
    // activations — peak ws extent = 221 MiB
    __bf16* xk = (__bf16*)(ws + 26 * MiB);   // stride to xv/xr = 32 MiB = 16M elems
    __bf16* xv = (__bf16*)(ws + 58 * MiB);
    __bf16* xr = (__bf16*)(ws + 90 * MiB);
    __bf16* kb = (__bf16*)(ws + 122 * MiB);  // stride to vb/sr = 32 MiB
    __bf16* vb = (__bf16*)(ws + 154 * MiB);
    __bf16* sr = (__bf16*)(ws + 186 * MiB);
    float* st_a = (float*)(ws + 218 * MiB);
    float* st_b = (float*)(ws + 219 * MiB);
    float* st_p = (float*)(ws + 220 * MiB);
    __bf16* atta = xk;
    __bf16* kx   = xv;
    __bf16* rx   = xr;
    __bf16* sb   = xk;
    __bf16* hb   = (__bf16*)(ws + 90 * MiB);

    // 1. weights -> bf16 (single fused launch)
    CvtArgs ca;
    ca.s[0] = aWk;  ca.d[0] = Wk_h;
    ca.s[1] = aWv;  ca.d[1] = Wv_h;
    ca.s[2] = aWr;  ca.d[2] = Wr_h;
    ca.s[3] = aWo;  ca.d[3] = Wo_h;
    ca.s[4] = fWk;  ca.d[4] = fWk_h;
    ca.s[5] = fWv;  ca.d[5] = fWv_h;
    ca.s[6] = fWr;  ca.d[6] = fWr_h;
    {
        const int sz[7] = {1<<18, 1<<18, 1<<18, 1<<18, 1<<20, 1<<20, 1<<18};
        int c = 0;
        for (int i = 0; i < 7; ++i) { ca.cum[i] = c; c += sz[i]; }
        ca.cum[7] = c;
    }
    cvt_all<<<(ca.cum[7] + 255) / 256, 256, 0, stream>>>(ca);

    // 2. attention LN + shift + mix
    ln_mix3<<<MROWS, 256, 0, stream>>>(x, lnaw, lnab, amk, amv, amr, xk, xv, xr);

    // 3. k, v, sigmoid(r) — single merged dispatch (3 slabs x 256 blocks)
    gemm8<7><<<768, 512, 0, stream>>>(xk, Wk_h, nullptr, kb, nullptr, nullptr, DDIM, DDIM, DDIM/256);

    // 4. WKV chunk-parallel scan -> sigmoid(r) * wkv (bf16), into xk region
    const int nthreads = BSZ * DDIM * NCHUNK;
    wkv_phase1<<<nthreads / 256, 256, 0, stream>>>(kb, vb, tdec, st_a, st_b, st_p);
    wkv_phase2<<<nthreads / 256, 256, 0, stream>>>(kb, vb, sr, tdec, tfir,
                                                   st_a, st_b, st_p, atta);

    // 5. att output projection + residual -> d_out (= x_new)
    gemm8<3><<<256, 512, 0, stream>>>(atta, Wo_h, out, nullptr, x, nullptr, DDIM, DDIM, DDIM/256);

    // 6. FFN LN + shift + mix (reads d_out)
    ln_mix2<<<MROWS, 256, 0, stream>>>(out, lnfw, lnfb, fmk, fmr, kx, rx);

    // 7a. s = sigmoid(rx @ fWr^T)  (before h so rx region can be reused)
    gemm8<1><<<256, 512, 0, stream>>>(rx, fWr_h, nullptr, sb, nullptr, nullptr, DDIM, DDIM, DDIM/256);

    // 7b. h = relu(kx @ fWk^T)^2
    gemm8<2><<<1024, 512, 0, stream>>>(kx, fWk_h, nullptr, hb, nullptr, nullptr, FDIM, DDIM, FDIM/256);

    // 8. d_out = x_new + s * (h @ fWv^T)
    gemm8<4><<<256, 512, 0, stream>>>(hb, fWv_h, out, nullptr, out, sb, DDIM, FDIM, DDIM/256);
}

// Round 11
// 702.605 us; speedup vs baseline: 1.4469x; 1.0176x over previous
//
#include <hip/hip_runtime.h>
#include <stdint.h>

// Problem dims (fixed by harness)
#define DDIM 1024
#define LSEQ 2048
#define BSZ  8
#define FDIM 4096
#define MROWS (BSZ*LSEQ)   // 16384
#define NCHUNK 32
#define CLEN  (LSEQ/NCHUNK)   // 64

typedef float        f32x4  __attribute__((ext_vector_type(4)));
typedef unsigned int u32x4  __attribute__((ext_vector_type(4)));

using gas_void = const __attribute__((address_space(1))) void;
using las_void = __attribute__((address_space(3))) void;

__device__ __forceinline__ void gload16(const void* g, void* l) {
    // async global->LDS; LDS dest = wave-uniform base + lane*16
    __builtin_amdgcn_global_load_lds((gas_void*)g, (las_void*)l, 16, 0, 0);
}

__device__ __forceinline__ void mfma_bf16(f32x4& d, u32x4 a, u32x4 b) {
    asm("v_mfma_f32_16x16x32_bf16 %0, %1, %2, %0" : "+v"(d) : "v"(a), "v"(b));
}

__device__ __forceinline__ unsigned short f2bf(float f) {
    __bf16 h = (__bf16)f;
    return __builtin_bit_cast(unsigned short, h);
}

// ---------------- fused weight fp32 -> bf16 (all 7 matrices, 1 launch) ----------------
struct CvtArgs {
    const float* s[7];
    __bf16*      d[7];
    int          cum[8];
};

__global__ __launch_bounds__(256) void cvt_all(CvtArgs a)
{
    const int i = blockIdx.x * 256 + threadIdx.x;
    if (i >= a.cum[7]) return;
    int seg = 0;
#pragma unroll 6
    while (i >= a.cum[seg + 1]) ++seg;
    const int off = i - a.cum[seg];
    float4 f = ((const float4*)a.s[seg])[off];
    ushort4 o;
    o.x = f2bf(f.x); o.y = f2bf(f.y); o.z = f2bf(f.z); o.w = f2bf(f.w);
    ((ushort4*)a.d[seg])[off] = o;
}

// ---------------- block reduce (4 scalars over 256 threads) ----------------
__device__ __forceinline__ void blk_reduce4(float& a, float& b, float& c, float& d) {
#pragma unroll
    for (int off = 32; off >= 1; off >>= 1) {
        a += __shfl_xor(a, off, 64);
        b += __shfl_xor(b, off, 64);
        c += __shfl_xor(c, off, 64);
        d += __shfl_xor(d, off, 64);
    }
    __shared__ float sm[4][4];
    const int tid = threadIdx.x;
    if ((tid & 63) == 0) {
        sm[tid >> 6][0] = a; sm[tid >> 6][1] = b;
        sm[tid >> 6][2] = c; sm[tid >> 6][3] = d;
    }
    __syncthreads();
    a = sm[0][0] + sm[1][0] + sm[2][0] + sm[3][0];
    b = sm[0][1] + sm[1][1] + sm[2][1] + sm[3][1];
    c = sm[0][2] + sm[1][2] + sm[2][2] + sm[3][2];
    d = sm[0][3] + sm[1][3] + sm[2][3] + sm[3][3];
}

// ---------------- LN + time_shift + mix (attention: 3 outputs) ----------------
__global__ __launch_bounds__(256) void ln_mix3(
    const float* __restrict__ xin, const float* __restrict__ lnw, const float* __restrict__ lnb,
    const float* __restrict__ mkv, const float* __restrict__ mvv, const float* __restrict__ mrv,
    __bf16* __restrict__ ok, __bf16* __restrict__ ov, __bf16* __restrict__ orr)
{
    const int row = blockIdx.x;
    const int l   = row & (LSEQ - 1);
    const int tid = threadIdx.x;
    const size_t rbase = (size_t)row * DDIM;
    const float4 cur = ((const float4*)(xin + rbase))[tid];
    float4 prv = make_float4(0.f, 0.f, 0.f, 0.f);
    if (l > 0) prv = ((const float4*)(xin + rbase - DDIM))[tid];
    float s0 = cur.x + cur.y + cur.z + cur.w;
    float q0 = cur.x*cur.x + cur.y*cur.y + cur.z*cur.z + cur.w*cur.w;
    float s1 = prv.x + prv.y + prv.z + prv.w;
    float q1 = prv.x*prv.x + prv.y*prv.y + prv.z*prv.z + prv.w*prv.w;
    blk_reduce4(s0, q0, s1, q1);
    const float inv = 1.f / (float)DDIM;
    const float m0 = s0 * inv, m1 = s1 * inv;
    const float r0 = rsqrtf(fmaxf(q0 * inv - m0*m0, 0.f) + 1e-5f);
    const float r1 = rsqrtf(fmaxf(q1 * inv - m1*m1, 0.f) + 1e-5f);
    const float4 w4 = ((const float4*)lnw)[tid];
    const float4 b4 = ((const float4*)lnb)[tid];
    const float4 k4 = ((const float4*)mkv)[tid];
    const float4 v4 = ((const float4*)mvv)[tid];
    const float4 r4 = ((const float4*)mrv)[tid];
    const float cA[4] = {cur.x, cur.y, cur.z, cur.w};
    const float pA[4] = {prv.x, prv.y, prv.z, prv.w};
    const float wA[4] = {w4.x, w4.y, w4.z, w4.w};
    const float bA[4] = {b4.x, b4.y, b4.z, b4.w};
    const float kA[4] = {k4.x, k4.y, k4.z, k4.w};
    const float vA[4] = {v4.x, v4.y, v4.z, v4.w};
    const float rA[4] = {r4.x, r4.y, r4.z, r4.w};
    ushort4 pk, pv, pr;
    unsigned short* pkp = &pk.x; unsigned short* pvp = &pv.x; unsigned short* prp = &pr.x;
#pragma unroll
    for (int j = 0; j < 4; ++j) {
        float xa = (cA[j] - m0) * r0 * wA[j] + bA[j];
        float xs = (l > 0) ? ((pA[j] - m1) * r1 * wA[j] + bA[j]) : 0.f;
        pkp[j] = f2bf(xa * kA[j] + xs * (1.f - kA[j]));
        pvp[j] = f2bf(xa * vA[j] + xs * (1.f - vA[j]));
        prp[j] = f2bf(xa * rA[j] + xs * (1.f - rA[j]));
    }
    const size_t oi = (size_t)row * (DDIM/4) + tid;
    ((ushort4*)ok)[oi]  = pk;
    ((ushort4*)ov)[oi]  = pv;
    ((ushort4*)orr)[oi] = pr;
}

// ---------------- LN + time_shift + mix (FFN: 2 outputs) ----------------
__global__ __launch_bounds__(256) void ln_mix2(
    const float* __restrict__ xin, const float* __restrict__ lnw, const float* __restrict__ lnb,
    const float* __restrict__ mkv, const float* __restrict__ mrv,
    __bf16* __restrict__ ok, __bf16* __restrict__ orr)
{
    const int row = blockIdx.x;
    const int l   = row & (LSEQ - 1);
    const int tid = threadIdx.x;
    const size_t rbase = (size_t)row * DDIM;
    const float4 cur = ((const float4*)(xin + rbase))[tid];
    float4 prv = make_float4(0.f, 0.f, 0.f, 0.f);
    if (l > 0) prv = ((const float4*)(xin + rbase - DDIM))[tid];
    float s0 = cur.x + cur.y + cur.z + cur.w;
    float q0 = cur.x*cur.x + cur.y*cur.y + cur.z*cur.z + cur.w*cur.w;
    float s1 = prv.x + prv.y + prv.z + prv.w;
    float q1 = prv.x*prv.x + prv.y*prv.y + prv.z*prv.z + prv.w*prv.w;
    blk_reduce4(s0, q0, s1, q1);
    const float inv = 1.f / (float)DDIM;
    const float m0 = s0 * inv, m1 = s1 * inv;
    const float r0 = rsqrtf(fmaxf(q0 * inv - m0*m0, 0.f) + 1e-5f);
    const float r1 = rsqrtf(fmaxf(q1 * inv - m1*m1, 0.f) + 1e-5f);
    const float4 w4 = ((const float4*)lnw)[tid];
    const float4 b4 = ((const float4*)lnb)[tid];
    const float4 k4 = ((const float4*)mkv)[tid];
    const float4 r4 = ((const float4*)mrv)[tid];
    const float cA[4] = {cur.x, cur.y, cur.z, cur.w};
    const float pA[4] = {prv.x, prv.y, prv.z, prv.w};
    const float wA[4] = {w4.x, w4.y, w4.z, w4.w};
    const float bA[4] = {b4.x, b4.y, b4.z, b4.w};
    const float kA[4] = {k4.x, k4.y, k4.z, k4.w};
    const float rA[4] = {r4.x, r4.y, r4.z, r4.w};
    ushort4 pk, pr;
    unsigned short* pkp = &pk.x; unsigned short* prp = &pr.x;
#pragma unroll
    for (int j = 0; j < 4; ++j) {
        float xa = (cA[j] - m0) * r0 * wA[j] + bA[j];
        float xs = (l > 0) ? ((pA[j] - m1) * r1 * wA[j] + bA[j]) : 0.f;
        pkp[j] = f2bf(xa * kA[j] + xs * (1.f - kA[j]));
        prp[j] = f2bf(xa * rA[j] + xs * (1.f - rA[j]));
    }
    const size_t oi = (size_t)row * (DDIM/4) + tid;
    ((ushort4*)ok)[oi]  = pk;
    ((ushort4*)orr)[oi] = pr;
}

// ---------------- WKV chunk-parallel scan ----------------
__global__ __launch_bounds__(256) void wkv_phase1(
    const __bf16* __restrict__ kin, const __bf16* __restrict__ vin,
    const float* __restrict__ td,
    float* __restrict__ sa, float* __restrict__ sb, float* __restrict__ sp)
{
    const int idx = blockIdx.x * 256 + threadIdx.x;
    const int d  = idx & (DDIM - 1);
    const int bc = idx >> 10;
    const int b  = bc & (BSZ - 1);
    const int c  = bc >> 3;
    const float w = -__expf(td[d]);
    const size_t base = ((size_t)b * LSEQ + (size_t)c * CLEN) * DDIM + d;
    float a = 0.f, bbv = 0.f, p = -1e38f;
    for (int t = 0; t < CLEN; ++t) {
        const size_t off = base + (size_t)t * DDIM;
        const float kt = (float)kin[off];
        const float vt = (float)vin[off];
        const float ww2 = p + w;
        const float q2  = fmaxf(ww2, kt);
        const float e1  = __expf(ww2 - q2);
        const float e2  = __expf(kt - q2);
        a   = e1 * a   + e2 * vt;
        bbv = e1 * bbv + e2;
        p   = q2;
    }
    sa[idx] = a; sb[idx] = bbv; sp[idx] = p;
}

__global__ __launch_bounds__(256) void wkv_phase2(
    const __bf16* __restrict__ kin, const __bf16* __restrict__ vin,
    const __bf16* __restrict__ srin,
    const float* __restrict__ td, const float* __restrict__ tf,
    const float* __restrict__ sa, const float* __restrict__ sb,
    const float* __restrict__ sp,
    __bf16* __restrict__ outp)
{
    const int idx = blockIdx.x * 256 + threadIdx.x;
    const int d  = idx & (DDIM - 1);
    const int bc = idx >> 10;
    const int b  = bc & (BSZ - 1);
    const int c  = bc >> 3;
    const float w = -__expf(td[d]);
    const float u = tf[d];
    const float nw = (float)CLEN * w;

    float a = 0.f, bbv = 0.f, p = -1e38f;
    for (int j = 0; j < c; ++j) {
        const int sidx = ((j * BSZ + b) << 10) + d;
        const float aj = sa[sidx], bj = sb[sidx], pj = sp[sidx];
        const float ps = p + nw;
        const float pn = fmaxf(ps, pj);
        const float e1 = __expf(ps - pn);
        const float e2 = __expf(pj - pn);
        a   = e1 * a   + e2 * aj;
        bbv = e1 * bbv + e2 * bj;
        p   = pn;
    }

    const size_t base = ((size_t)b * LSEQ + (size_t)c * CLEN) * DDIM + d;
    for (int t = 0; t < CLEN; ++t) {
        const size_t off = base + (size_t)t * DDIM;
        const float kt = (float)kin[off];
        const float vt = (float)vin[off];
        const float sr = (float)srin[off];
        const float ww = u + kt;
        const float q  = fmaxf(p, ww);
        const float e1 = __expf(p - q);
        const float e2 = __expf(ww - q);
        const float o  = (e1 * a + e2 * vt) / (e1 * bbv + e2);
        outp[off] = (__bf16)(sr * o);
        const float ww2 = p + w;
        const float q2  = fmaxf(ww2, kt);
        const float e1b = __expf(ww2 - q2);
        const float e2b = __expf(kt - q2);
        a   = e1b * a   + e2b * vt;
        bbv = e1b * bbv + e2b;
        p   = q2;
    }
}

// ---------------- 256x128 simple-loop bf16 GEMM, 2-3 blocks/CU TLP ----------------
// C[M,N] = A[M,K] @ B[N,K]^T. 8 waves (4 wr x 2 wc), wave tile 64x64, BK=64,
// single-buffered 48 KiB LDS, 2 syncthreads/K-tile (m97 regime: cross-block drift
// hides drain), XOR-swizzled 128B LDS rows (2-way banks = free), asm MFMA
// (R3-validated; builtin bloats VGPR -> occupancy tier loss, see R9).
// __launch_bounds__(512,4): cap regs at 128/wave -> 2 blocks/CU (16 waves).
// EPI: 1 sigmoid->bf16; 2 relu^2->bf16; 3 auxF+acc->f32; 4 auxF+auxH*acc->f32;
//      5 bf16; 7 kvr-merged (3 slabs of 512 blocks; slab2 sigmoid)
template<int EPI>
__global__ __launch_bounds__(512, 4)
void gemm_s(const __bf16* __restrict__ A, const __bf16* __restrict__ Bw,
            float* outF, __bf16* outH,
            const float* auxF, const __bf16* __restrict__ auxH,
            int N, int K, int gy)
{
    __shared__ __align__(16) char smem[49152];   // A: 32 KiB @0, B: 16 KiB @32768
    const int tid  = threadIdx.x;
    const int lane = tid & 63;
    const int wid  = tid >> 6;
    const int wr = wid >> 1, wc = wid & 1;       // 4 x 2 waves

    int f = blockIdx.x;
    int nwg = gridDim.x;
    bool sig = false;
    if constexpr (EPI == 7) {
        const int slab = f / 512;
        f -= slab * 512; nwg = 512;
        A    += (size_t)slab * (16u << 20);   // xk/xv/xr stride 16M elems
        Bw   += (size_t)slab << 20;           // Wk|Wv|Wr stride 1M elems
        outH += (size_t)slab << 24;           // kb|vb|sr stride 16M elems
        sig = (slab == 2);
    }
    // XCD-bijective remap (nwg % 8 == 0), gy-major: consecutive g share A-panel
    const int g = (f & 7) * (nwg >> 3) + (f >> 3);
    const int tx = g / gy;
    const int ty = g - tx * gy;
    const size_t row0 = (size_t)tx * 256;
    const size_t col0 = (size_t)ty * 128;

    // LDS image: row r (128B) holds global k-chunk (slot ^ (r&7)) at slot*16.
    // Stage: linear dest (wave-uniform + lane*16); source chunk = (lane&7)^(row&7).
    f32x4 acc[4][4] = {};

    for (int kt = 0; kt < K; kt += 64) {
        __syncthreads();                  // previous reads done before overwrite
        // stage A: wave covers rows [wid*32, wid*32+32): 4 gloads
#pragma unroll
        for (int q = 0; q < 4; ++q) {
            const int row   = wid * 32 + q * 8 + (lane >> 3);
            const int chunk = (lane & 7) ^ (row & 7);
            gload16(A + (row0 + row) * (size_t)K + kt + chunk * 8,
                    smem + wid * 4096 + q * 1024);
        }
        // stage B: wave covers rows [wid*16, wid*16+16): 2 gloads
#pragma unroll
        for (int q = 0; q < 2; ++q) {
            const int row   = wid * 16 + q * 8 + (lane >> 3);
            const int chunk = (lane & 7) ^ (row & 7);
            gload16(Bw + (col0 + row) * (size_t)K + kt + chunk * 8,
                    smem + 32768 + wid * 2048 + q * 1024);
        }
        __syncthreads();                  // drains vmcnt(0), publishes tile

#pragma unroll
        for (int kh = 0; kh < 2; ++kh) {
            u32x4 bf[4];
#pragma unroll
            for (int n = 0; n < 4; ++n) {
                const int row  = wc * 64 + n * 16 + (lane & 15);
                const int slot = (kh * 4 + (lane >> 4)) ^ (row & 7);
                bf[n] = *(const u32x4*)(smem + 32768 + row * 128 + slot * 16);
            }
#pragma unroll
            for (int m = 0; m < 4; ++m) {
                const int row  = wr * 64 + m * 16 + (lane & 15);
                const int slot = (kh * 4 + (lane >> 4)) ^ (row & 7);
                const u32x4 af = *(const u32x4*)(smem + row * 128 + slot * 16);
#pragma unroll
                for (int n = 0; n < 4; ++n)
                    mfma_bf16(acc[m][n], af, bf[n]);
            }
        }
    }
    asm volatile("s_nop 7\n\ts_nop 7\n\ts_nop 3");

    // C/D layout: col = lane&15, row = 4*(lane>>4) + reg  [verified r2-r10]
    const size_t obr = row0 + wr * 64 + ((lane >> 4) << 2);
    const size_t obc = col0 + wc * 64 + (lane & 15);
#pragma unroll
    for (int m = 0; m < 4; ++m) {
#pragma unroll
        for (int n = 0; n < 4; ++n) {
#pragma unroll
            for (int j = 0; j < 4; ++j) {
                const size_t idx = (obr + m * 16 + j) * (size_t)N + obc + n * 16;
                const float v = acc[m][n][j];
                if constexpr (EPI == 1) {
                    outH[idx] = (__bf16)(1.f / (1.f + __expf(-v)));
                } else if constexpr (EPI == 2) {
                    const float t2 = fmaxf(v, 0.f);
                    outH[idx] = (__bf16)(t2 * t2);
                } else if constexpr (EPI == 3) {
                    outF[idx] = auxF[idx] + v;
                } else if constexpr (EPI == 4) {
                    outF[idx] = auxF[idx] + (float)auxH[idx] * v;
                } else if constexpr (EPI == 7) {
                    outH[idx] = (__bf16)(sig ? (1.f / (1.f + __expf(-v))) : v);
                } else {
                    outH[idx] = (__bf16)v;
                }
            }
        }
    }
}

extern "C" void kernel_launch(void* const* d_in, const int* in_sizes, int n_in,
                              void* d_out, int out_size, void* d_ws, size_t ws_size,
                              hipStream_t stream)
{
    const float* x    = (const float*)d_in[0];
    const float* lnaw = (const float*)d_in[1];
    const float* lnab = (const float*)d_in[2];
    const float* lnfw = (const float*)d_in[3];
    const float* lnfb = (const float*)d_in[4];
    const float* tdec = (const float*)d_in[5];
    const float* tfir = (const float*)d_in[6];
    const float* amk  = (const float*)d_in[7];
    const float* amv  = (const float*)d_in[8];
    const float* amr  = (const float*)d_in[9];
    const float* aWk  = (const float*)d_in[10];
    const float* aWv  = (const float*)d_in[11];
    const float* aWr  = (const float*)d_in[12];
    const float* aWo  = (const float*)d_in[13];
    const float* fmk  = (const float*)d_in[14];
    const float* fmr  = (const float*)d_in[15];
    const float* fWk  = (const float*)d_in[16];
    const float* fWv  = (const float*)d_in[17];
    const float* fWr  = (const float*)d_in[18];
    float* out = (float*)d_out;

    char* ws = (char*)d_ws;
    const size_t MiB = 1ull << 20;
    __bf16* Wk_h  = (__bf16*)ws;
    __bf16* Wv_h  = Wk_h + (1ull << 20);
    __bf16* Wr_h  = Wk_h + (2ull << 20);
    __bf16* Wo_h  = Wk_h + (3ull << 20);
    __bf16* fWk_h = Wk_h + (4ull << 20);
    __bf16* fWv_h = Wk_h + (8ull << 20);
    __bf16* fWr_h = Wk_h + (12ull << 20);
    // activations — peak ws extent = 221 MiB
    __bf16* xk = (__bf16*)(ws + 26 * MiB);   // stride to xv/xr = 32 MiB
    __bf16* xv = (__bf16*)(ws + 58 * MiB);
    __bf16* xr = (__bf16*)(ws + 90 * MiB);
    __bf16* kb = (__bf16*)(ws + 122 * MiB);  // stride to vb/sr = 32 MiB
    __bf16* vb = (__bf16*)(ws + 154 * MiB);
    __bf16* sr = (__bf16*)(ws + 186 * MiB);
    float* st_a = (float*)(ws + 218 * MiB);
    float* st_b = (float*)(ws + 219 * MiB);
    float* st_p = (float*)(ws + 220 * MiB);
    __bf16* atta = xk;
    __bf16* kx   = xv;
    __bf16* rx   = xr;
    __bf16* sb   = xk;
    __bf16* hb   = (__bf16*)(ws + 90 * MiB);

    // 1. weights -> bf16 (single fused launch)
    CvtArgs ca;
    ca.s[0] = aWk;  ca.d[0] = Wk_h;
    ca.s[1] = aWv;  ca.d[1] = Wv_h;
    ca.s[2] = aWr;  ca.d[2] = Wr_h;
    ca.s[3] = aWo;  ca.d[3] = Wo_h;
    ca.s[4] = fWk;  ca.d[4] = fWk_h;
    ca.s[5] = fWv;  ca.d[5] = fWv_h;
    ca.s[6] = fWr;  ca.d[6] = fWr_h;
    {
        const int sz[7] = {1<<18, 1<<18, 1<<18, 1<<18, 1<<20, 1<<20, 1<<18};
        int c = 0;
        for (int i = 0; i < 7; ++i) { ca.cum[i] = c; c += sz[i]; }
        ca.cum[7] = c;
    }
    cvt_all<<<(ca.cum[7] + 255) / 256, 256, 0, stream>>>(ca);

    // 2. attention LN + shift + mix
    ln_mix3<<<MROWS, 256, 0, stream>>>(x, lnaw, lnab, amk, amv, amr, xk, xv, xr);

    // 3. k, v, sigmoid(r) — merged dispatch (3 slabs x 512 blocks of 256x128)
    gemm_s<7><<<1536, 512, 0, stream>>>(xk, Wk_h, nullptr, kb, nullptr, nullptr, DDIM, DDIM, DDIM/128);

    // 4. WKV chunk-parallel scan -> sigmoid(r) * wkv (bf16), into xk region
    const int nthreads = BSZ * DDIM * NCHUNK;
    wkv_phase1<<<nthreads / 256, 256, 0, stream>>>(kb, vb, tdec, st_a, st_b, st_p);
    wkv_phase2<<<nthreads / 256, 256, 0, stream>>>(kb, vb, sr, tdec, tfir,
                                                   st_a, st_b, st_p, atta);

    // 5. att output projection + residual -> d_out (= x_new)
    gemm_s<3><<<512, 512, 0, stream>>>(atta, Wo_h, out, nullptr, x, nullptr, DDIM, DDIM, DDIM/128);

    // 6. FFN LN + shift + mix (reads d_out)
    ln_mix2<<<MROWS, 256, 0, stream>>>(out, lnfw, lnfb, fmk, fmr, kx, rx);

    // 7a. s = sigmoid(rx @ fWr^T)  (before h so rx region can be reused)
    gemm_s<1><<<512, 512, 0, stream>>>(rx, fWr_h, nullptr, sb, nullptr, nullptr, DDIM, DDIM, DDIM/128);

    // 7b. h = relu(kx @ fWk^T)^2
    gemm_s<2><<<2048, 512, 0, stream>>>(kx, fWk_h, nullptr, hb, nullptr, nullptr, FDIM, DDIM, FDIM/128);

    // 8. d_out = x_new + s * (h @ fWv^T)
    gemm_s<4><<<512, 512, 0, stream>>>(hb, fWv_h, out, nullptr, out, sb, DDIM, FDIM, DDIM/128);
}